// Round 11
// baseline (569.339 us; speedup 1.0000x reference)
//
#include <hip/hip_runtime.h>
#include <hip/hip_bf16.h>

#define NG 64       // NUM_GROUPS
#define TOPK 8
#define BM 128      // BLOCK_M
#define NSLOT 65536 // NUM_TOKENS * TOPK
#define HID 4096
#define NTOK 8192
#define NSEG 64     // segments of 1024 ids each

typedef unsigned int v4u __attribute__((ext_vector_type(4)));

// ws ints:
// [0..63]     out_start[e]
// [64..127]   cnt[e]
// [128..191]  padded[e]
// [192..255]  lastslot[e]
// [256]       total
// [257]       ticket counter (never reset; winner = (old & 63)==63)
// [320..4415] segcnt[e*64+s]
// [4416..8511] lastm[e*64+s]
// rank u16 at ws + 8704 ints (131072 B) -> scratch ~166 KB

// K1: per-segment hist, then last-arriving block performs the expert scan.
__global__ __launch_bounds__(256) void hist_scan_k(const int* __restrict__ ids,
                                                   int* __restrict__ ws) {
    __shared__ int h[NG], lm[NG];
    __shared__ int winner;
    int t = threadIdx.x, s = blockIdx.x;
    if (t < NG) { h[t] = 0; lm[t] = -1; }
    __syncthreads();
    int base = s * 1024;
    for (int i = t; i < 1024; i += 256) {
        int e = ids[base + i] & (NG - 1);
        atomicAdd(&h[e], 1);
        atomicMax(&lm[e], base + i);
    }
    __syncthreads();
    if (t < NG) {
        ws[320 + t * 64 + s] = h[t];
        ws[4416 + t * 64 + s] = lm[t];
    }
    __threadfence();  // device-scope release of this block's segcnt/lastm
    __syncthreads();
    if (t == 0) {
        unsigned old = atomicAdd((unsigned*)&ws[257], 1u);
        winner = ((old & 63u) == 63u) ? 1 : 0;  // exactly one winner per 64 adds
    }
    __syncthreads();
    if (!winner) return;
    __threadfence();  // acquire: all 64 blocks' publishes visible
    if (t < NG) {
        int e = t, c = 0, last = -1;
        for (int b = 0; b < NSEG; b++) {
            c += ws[320 + e * 64 + b];
            int l = ws[4416 + e * 64 + b];
            last = l > last ? l : last;
        }
        ws[64 + e] = c;
        ws[128 + e] = (c + BM - 1) / BM * BM;
        ws[192 + e] = last;
    }
    __syncthreads();
    if (t == 0) {
        int acc = 0;
        for (int f = 0; f < NG; f++) { ws[f] = acc; acc += ws[128 + f]; }
        ws[256] = acc;  // total
    }
}

// K2: one wave per segment; lane e self-computes its within-expert base
// (prefix of segcnt over earlier segments), then ballot-ranks the segment.
// Full-wave contiguous u16 stores (one wave per rank[] line).
__global__ __launch_bounds__(64) void rank_k(const int* __restrict__ ids,
                                             const int* __restrict__ ws,
                                             unsigned short* __restrict__ rank) {
    int s = blockIdx.x;
    int lane = threadIdx.x;
    int base = 0;
    for (int s2 = 0; s2 < s; s2++) base += ws[320 + lane * 64 + s2];
    int segbase = s * 1024;
    unsigned long long below = (1ULL << lane) - 1ULL;
    for (int c0 = 0; c0 < 1024; c0 += 64) {
        int e = ids[segbase + c0 + lane] & (NG - 1);
        int r = 0;
#pragma unroll 8
        for (int x = 0; x < NG; x++) {
            unsigned long long m = __ballot(e == x);
            if (m) {
                int bx = __shfl(base, x);
                if (e == x) r = bx + __popcll(m & below);
                if (lane == x) base += (int)__popcll(m);
            }
        }
        rank[segbase + c0 + lane] = (unsigned short)r;
    }
}

// K3: token-grouped scatter + m_indices + inv_perm (trailing blocks).
// Streaming data uses non-temporal loads/stores (write-once / read-once:
// no reuse => bypass L2/L3 allocation, keep cache BW for the stream).
__global__ __launch_bounds__(256) void copy_k(const __hip_bfloat16* __restrict__ hs,
                                              const int* __restrict__ ids,
                                              const int* __restrict__ ws,
                                              const unsigned short* __restrict__ rank,
                                              float* __restrict__ out) {
    __shared__ int s_last[NG], s_pad[NG];
    int b = blockIdx.x;
    int total = ws[256];
    int t = threadIdx.x;
    float* m_out = out + (size_t)total * HID;
    if (b < NTOK) {
        const v4u* s = (const v4u*)(hs + (size_t)b * HID);
        v4u w0 = __builtin_nontemporal_load(s + t);
        v4u w1 = __builtin_nontemporal_load(s + t + 256);
        v4u a0 = {w0.x << 16, w0.x & 0xFFFF0000u, w0.y << 16, w0.y & 0xFFFF0000u};
        v4u a1 = {w0.z << 16, w0.z & 0xFFFF0000u, w0.w << 16, w0.w & 0xFFFF0000u};
        v4u a2 = {w1.x << 16, w1.x & 0xFFFF0000u, w1.y << 16, w1.y & 0xFFFF0000u};
        v4u a3 = {w1.z << 16, w1.z & 0xFFFF0000u, w1.w << 16, w1.w & 0xFFFF0000u};
        int slot0 = b * TOPK;
#pragma unroll
        for (int k = 0; k < TOPK; k++) {
            int e = ids[slot0 + k] & (NG - 1);
            int dst = ws[e] + (int)rank[slot0 + k];
            if (dst < 0 || dst >= total) continue;
            v4u* d = (v4u*)(out + (size_t)dst * HID);
            __builtin_nontemporal_store(a0, d + 2 * t);
            __builtin_nontemporal_store(a1, d + 2 * t + 1);
            __builtin_nontemporal_store(a2, d + 2 * (t + 256));
            __builtin_nontemporal_store(a3, d + 2 * (t + 256) + 1);
            if (t == 0) m_out[dst] = (float)e;
        }
    } else if (b < NTOK + NG * BM) {
        int q = b - NTOK;
        int e = q >> 7;
        int j = q & 127;
        int c = ws[64 + e], p = ws[128 + e];
        if (c + j >= p) return;
        int srcslot = ws[192 + e];
        int dst = ws[e] + c + j;
        if (dst < 0 || dst >= total) return;
        int src = srcslot >> 3;
        if (src < 0 || src >= NTOK) return;
        if (t == 0) m_out[dst] = (float)e;
        const v4u* s = (const v4u*)(hs + (size_t)src * HID);
        v4u* d = (v4u*)(out + (size_t)dst * HID);
#pragma unroll
        for (int half = 0; half < 2; half++) {
            int v = half * 256 + t;
            v4u w = s[v];  // pad source rows are re-read ~128x: leave cached
            v4u o1 = {w.x << 16, w.x & 0xFFFF0000u, w.y << 16, w.y & 0xFFFF0000u};
            v4u o2 = {w.z << 16, w.z & 0xFFFF0000u, w.w << 16, w.w & 0xFFFF0000u};
            __builtin_nontemporal_store(o1, d + 2 * v);
            __builtin_nontemporal_store(o2, d + 2 * v + 1);
        }
    } else {
        // inv_perm: inv[v + sum_{f: last_f < v} pad_f] = pos(v); pads follow last slot.
        if (t < NG) {
            s_last[t] = ws[192 + t];
            s_pad[t] = ws[128 + t] - ws[64 + t];
        }
        __syncthreads();
        float* inv_out = out + (size_t)total * (HID + 1);
        int i = (b - NTOK - NG * BM) * 256 + t;
        int e = ids[i] & (NG - 1);
        int pos = ws[e] + (int)rank[i];
        int base = i;
#pragma unroll
        for (int f = 0; f < NG; f++) {
            int l = s_last[f];
            base += (l >= 0 && l < i) ? s_pad[f] : 0;
        }
        if (base < NSLOT) inv_out[base] = (float)pos;
        if (i == s_last[e]) {
            int oc = ws[e] + ws[64 + e];
            int pd = s_pad[e];
            for (int j = 0; j < pd; j++) {
                int idx = base + 1 + j;
                if (idx >= NSLOT) break;
                inv_out[idx] = (float)(oc + j);
            }
        }
    }
}

extern "C" void kernel_launch(void* const* d_in, const int* in_sizes, int n_in,
                              void* d_out, int out_size, void* d_ws, size_t ws_size,
                              hipStream_t stream) {
    const __hip_bfloat16* hs = (const __hip_bfloat16*)d_in[0];
    const int* ids = (const int*)d_in[1];
    float* out = (float*)d_out;  // mixed-dtype tuple => harness packs as float32

    int* ws = (int*)d_ws;
    unsigned short* rank = (unsigned short*)(ws + 8704);

    hipLaunchKernelGGL(hist_scan_k, dim3(NSEG), dim3(256), 0, stream, ids, ws);
    hipLaunchKernelGGL(rank_k, dim3(NSEG), dim3(64), 0, stream, ids, ws, rank);
    hipLaunchKernelGGL(copy_k, dim3(NTOK + NG * BM + NSLOT / 256), dim3(256), 0, stream,
                       hs, ids, ws, rank, out);
}

// Round 12
// 329.794 us; speedup vs baseline: 1.7263x; 1.7263x over previous
//
#include <hip/hip_runtime.h>
#include <hip/hip_bf16.h>

#define NG 64       // NUM_GROUPS
#define TOPK 8
#define BM 128      // BLOCK_M
#define NSLOT 65536 // NUM_TOKENS * TOPK
#define HID 4096
#define NTOK 8192
#define NSEG 64     // segments of 1024 ids each
#define MAXROWS 73664  // 65536 + 64*127 upper bound on total

typedef unsigned int v4u __attribute__((ext_vector_type(4)));

// ws ints:
// [0..63]     out_start[e]
// [64..127]   cnt[e]
// [128..191]  padded[e]
// [192..255]  lastslot[e]
// [256]       total
// [257]       ticket (never reset; winner = (old & 63)==63)
// [320..4415] segcnt[e*64+s]
// [4416..8511] lastm[e*64+s]
// rank   u16 at ws + 8704  (NSLOT entries, 128 KB)
// srcrow u16 at ws + 41472 (MAXROWS entries, 144 KB)  -> scratch ~310 KB

// K1: per-segment hist; last-arriving block scans experts and fills pad srcrow.
__global__ __launch_bounds__(256) void hist_scan_k(const int* __restrict__ ids,
                                                   int* __restrict__ ws,
                                                   unsigned short* __restrict__ srcrow) {
    __shared__ int h[NG], lm[NG];
    __shared__ int winner;
    int t = threadIdx.x, s = blockIdx.x;
    if (t < NG) { h[t] = 0; lm[t] = -1; }
    __syncthreads();
    int base = s * 1024;
    for (int i = t; i < 1024; i += 256) {
        int e = ids[base + i] & (NG - 1);
        atomicAdd(&h[e], 1);
        atomicMax(&lm[e], base + i);
    }
    __syncthreads();
    if (t < NG) {
        ws[320 + t * 64 + s] = h[t];
        ws[4416 + t * 64 + s] = lm[t];
    }
    __threadfence();
    __syncthreads();
    if (t == 0) {
        unsigned old = atomicAdd((unsigned*)&ws[257], 1u);
        winner = ((old & 63u) == 63u) ? 1 : 0;
    }
    __syncthreads();
    if (!winner) return;
    __threadfence();  // acquire all blocks' publishes
    if (t < NG) {
        int e = t, c = 0, last = -1;
        for (int b = 0; b < NSEG; b++) {
            c += ws[320 + e * 64 + b];
            int l = ws[4416 + e * 64 + b];
            last = l > last ? l : last;
        }
        ws[64 + e] = c;
        ws[128 + e] = (c + BM - 1) / BM * BM;
        ws[192 + e] = last;
    }
    __syncthreads();
    if (t == 0) {
        int acc = 0;
        for (int f = 0; f < NG; f++) { ws[f] = acc; acc += ws[128 + f]; }
        ws[256] = acc;  // total
    }
    __syncthreads();
    // fill srcrow for pad rows: rows [o+c, o+p) <- lastslot  (<=8128 entries)
    for (int e = 0; e < NG; e++) {
        int c = ws[64 + e], p = ws[128 + e];
        int o = ws[e];
        unsigned short ls = (unsigned short)ws[192 + e];
        for (int j = c + t; j < p; j += 256) srcrow[o + j] = ls;
    }
}

// K2: one wave per segment; lane e self-computes its within-expert base, then
// ballot-ranks. Writes rank[] (full-wave contiguous) AND srcrow[o_e + r] = slot.
__global__ __launch_bounds__(64) void rank_k(const int* __restrict__ ids,
                                             const int* __restrict__ ws,
                                             unsigned short* __restrict__ rank,
                                             unsigned short* __restrict__ srcrow) {
    int s = blockIdx.x;
    int lane = threadIdx.x;
    int base = 0;
    for (int s2 = 0; s2 < s; s2++) base += ws[320 + lane * 64 + s2];
    int segbase = s * 1024;
    unsigned long long below = (1ULL << lane) - 1ULL;
    for (int c0 = 0; c0 < 1024; c0 += 64) {
        int slot = segbase + c0 + lane;
        int e = ids[slot] & (NG - 1);
        int r = 0;
#pragma unroll 8
        for (int x = 0; x < NG; x++) {
            unsigned long long m = __ballot(e == x);
            if (m) {
                int bx = __shfl(base, x);
                if (e == x) r = bx + __popcll(m & below);
                if (lane == x) base += (int)__popcll(m);
            }
        }
        rank[slot] = (unsigned short)r;
        srcrow[ws[e] + r] = (unsigned short)slot;  // inverse perm for gather
    }
}

// K3: sequential-write gather + m_indices; trailing blocks do inv_perm.
// Block b < MAXROWS: writes output row b (blockIdx-ordered => near-sequential
// store stream, fill-kernel-like), reading hs[srcrow[b]>>3] (L3 reuse x8).
__global__ __launch_bounds__(256) void copy_k(const __hip_bfloat16* __restrict__ hs,
                                              const int* __restrict__ ids,
                                              const int* __restrict__ ws,
                                              const unsigned short* __restrict__ rank,
                                              const unsigned short* __restrict__ srcrow,
                                              float* __restrict__ out) {
    __shared__ int s_last[NG], s_pad[NG];
    int b = blockIdx.x;
    int total = ws[256];
    int t = threadIdx.x;
    if (b < MAXROWS) {
        if (b >= total) return;
        int slot = (int)srcrow[b];
        int src = slot >> 3;  // /TOPK
        if (t == 0) out[(size_t)total * HID + b] = (float)(ids[slot] & (NG - 1));
        const v4u* s = (const v4u*)(hs + (size_t)src * HID);
        v4u w0 = s[t];
        v4u w1 = s[t + 256];
        v4u a0 = {w0.x << 16, w0.x & 0xFFFF0000u, w0.y << 16, w0.y & 0xFFFF0000u};
        v4u a1 = {w0.z << 16, w0.z & 0xFFFF0000u, w0.w << 16, w0.w & 0xFFFF0000u};
        v4u a2 = {w1.x << 16, w1.x & 0xFFFF0000u, w1.y << 16, w1.y & 0xFFFF0000u};
        v4u a3 = {w1.z << 16, w1.z & 0xFFFF0000u, w1.w << 16, w1.w & 0xFFFF0000u};
        v4u* d = (v4u*)(out + (size_t)b * HID);
        d[2 * t] = a0;
        d[2 * t + 1] = a1;
        d[2 * (t + 256)] = a2;
        d[2 * (t + 256) + 1] = a3;
    } else {
        // inv_perm: inv[v + sum_{f: last_f < v} pad_f] = pos(v); pads follow last slot.
        if (t < NG) {
            s_last[t] = ws[192 + t];
            s_pad[t] = ws[128 + t] - ws[64 + t];
        }
        __syncthreads();
        float* inv_out = out + (size_t)total * (HID + 1);
        int i = (b - MAXROWS) * 256 + t;
        int e = ids[i] & (NG - 1);
        int pos = ws[e] + (int)rank[i];
        int base = i;
#pragma unroll
        for (int f = 0; f < NG; f++) {
            int l = s_last[f];
            base += (l >= 0 && l < i) ? s_pad[f] : 0;
        }
        if (base < NSLOT) inv_out[base] = (float)pos;
        if (i == s_last[e]) {
            int oc = ws[e] + ws[64 + e];
            int pd = s_pad[e];
            for (int j = 0; j < pd; j++) {
                int idx = base + 1 + j;
                if (idx >= NSLOT) break;
                inv_out[idx] = (float)(oc + j);
            }
        }
    }
}

extern "C" void kernel_launch(void* const* d_in, const int* in_sizes, int n_in,
                              void* d_out, int out_size, void* d_ws, size_t ws_size,
                              hipStream_t stream) {
    const __hip_bfloat16* hs = (const __hip_bfloat16*)d_in[0];
    const int* ids = (const int*)d_in[1];
    float* out = (float*)d_out;  // mixed-dtype tuple => harness packs as float32

    int* ws = (int*)d_ws;
    unsigned short* rank = (unsigned short*)(ws + 8704);
    unsigned short* srcrow = (unsigned short*)(ws + 41472);

    hipLaunchKernelGGL(hist_scan_k, dim3(NSEG), dim3(256), 0, stream, ids, ws, srcrow);
    hipLaunchKernelGGL(rank_k, dim3(NSEG), dim3(64), 0, stream, ids, ws, rank, srcrow);
    hipLaunchKernelGGL(copy_k, dim3(MAXROWS + NSLOT / 256), dim3(256), 0, stream,
                       hs, ids, ws, rank, srcrow, out);
}

// Round 13
// 298.509 us; speedup vs baseline: 1.9073x; 1.1048x over previous
//
#include <hip/hip_runtime.h>
#include <hip/hip_bf16.h>

#define NG 64       // NUM_GROUPS
#define TOPK 8
#define BM 128      // BLOCK_M
#define NSLOT 65536 // NUM_TOKENS * TOPK
#define HID 4096
#define NTOK 8192
#define NSEG 64     // segments of 1024 ids each

typedef unsigned int v4u __attribute__((ext_vector_type(4)));
typedef unsigned int v2u __attribute__((ext_vector_type(2)));

// ws ints:
// [0..63]     out_start[e]
// [64..127]   cnt[e]
// [128..191]  padded[e]
// [192..255]  lastslot[e]
// [256]       total
// [257]       ticket (never reset; winner = (old & 63)==63)
// [320..4415] segcnt[e*64+s]
// [4416..8511] lastm[e*64+s]
// rank u16 at ws + 8704 ints (131072 B) -> scratch ~166 KB

// K1: per-segment hist, then last-arriving block performs the expert scan.
__global__ __launch_bounds__(256) void hist_scan_k(const int* __restrict__ ids,
                                                   int* __restrict__ ws) {
    __shared__ int h[NG], lm[NG];
    __shared__ int winner;
    int t = threadIdx.x, s = blockIdx.x;
    if (t < NG) { h[t] = 0; lm[t] = -1; }
    __syncthreads();
    int base = s * 1024;
    for (int i = t; i < 1024; i += 256) {
        int e = ids[base + i] & (NG - 1);
        atomicAdd(&h[e], 1);
        atomicMax(&lm[e], base + i);
    }
    __syncthreads();
    if (t < NG) {
        ws[320 + t * 64 + s] = h[t];
        ws[4416 + t * 64 + s] = lm[t];
    }
    __threadfence();
    __syncthreads();
    if (t == 0) {
        unsigned old = atomicAdd((unsigned*)&ws[257], 1u);
        winner = ((old & 63u) == 63u) ? 1 : 0;
    }
    __syncthreads();
    if (!winner) return;
    __threadfence();
    if (t < NG) {
        int e = t, c = 0, last = -1;
        for (int b = 0; b < NSEG; b++) {
            c += ws[320 + e * 64 + b];
            int l = ws[4416 + e * 64 + b];
            last = l > last ? l : last;
        }
        ws[64 + e] = c;
        ws[128 + e] = (c + BM - 1) / BM * BM;
        ws[192 + e] = last;
    }
    __syncthreads();
    if (t == 0) {
        int acc = 0;
        for (int f = 0; f < NG; f++) { ws[f] = acc; acc += ws[128 + f]; }
        ws[256] = acc;  // total
    }
}

// K2: one wave per segment; lane e self-computes its within-expert base
// (prefix of segcnt over earlier segments), then ballot-ranks the segment.
__global__ __launch_bounds__(64) void rank_k(const int* __restrict__ ids,
                                             const int* __restrict__ ws,
                                             unsigned short* __restrict__ rank) {
    int s = blockIdx.x;
    int lane = threadIdx.x;
    int base = 0;
    for (int s2 = 0; s2 < s; s2++) base += ws[320 + lane * 64 + s2];
    int segbase = s * 1024;
    unsigned long long below = (1ULL << lane) - 1ULL;
    for (int c0 = 0; c0 < 1024; c0 += 64) {
        int e = ids[segbase + c0 + lane] & (NG - 1);
        int r = 0;
#pragma unroll 8
        for (int x = 0; x < NG; x++) {
            unsigned long long m = __ballot(e == x);
            if (m) {
                int bx = __shfl(base, x);
                if (e == x) r = bx + __popcll(m & below);
                if (lane == x) base += (int)__popcll(m);
            }
        }
        rank[segbase + c0 + lane] = (unsigned short)r;
    }
}

// K3: token-grouped scatter with per-instruction wave-contiguous stores:
// thread t owns f32 elements [4t,4t+4) of each row-quarter q; store instruction
// q covers a contiguous 4 KB (1 KB per wave) -> fill-kernel-like coalescing.
__global__ __launch_bounds__(256) void copy_k(const __hip_bfloat16* __restrict__ hs,
                                              const int* __restrict__ ids,
                                              const int* __restrict__ ws,
                                              const unsigned short* __restrict__ rank,
                                              float* __restrict__ out) {
    __shared__ int s_last[NG], s_pad[NG];
    int b = blockIdx.x;
    int total = ws[256];
    int t = threadIdx.x;
    float* m_out = out + (size_t)total * HID;
    if (b < NTOK) {
        const v2u* s2 = (const v2u*)(hs + (size_t)b * HID);  // 1024 x 8B
        v4u a[4];
#pragma unroll
        for (int q = 0; q < 4; q++) {
            v2u w = s2[t + 256 * q];
            a[q].x = w.x << 16; a[q].y = w.x & 0xFFFF0000u;
            a[q].z = w.y << 16; a[q].w = w.y & 0xFFFF0000u;
        }
        int slot0 = b * TOPK;
#pragma unroll
        for (int k = 0; k < TOPK; k++) {
            int e = ids[slot0 + k] & (NG - 1);
            int dst = ws[e] + (int)rank[slot0 + k];
            if (dst < 0 || dst >= total) continue;
            v4u* d = (v4u*)(out + (size_t)dst * HID);  // 1024 x 16B
#pragma unroll
            for (int q = 0; q < 4; q++) d[t + 256 * q] = a[q];
            if (t == 0) m_out[dst] = (float)e;
        }
    } else if (b < NTOK + NG * BM) {
        int q0 = b - NTOK;
        int e = q0 >> 7;
        int j = q0 & 127;
        int c = ws[64 + e], p = ws[128 + e];
        if (c + j >= p) return;
        int srcslot = ws[192 + e];
        int dst = ws[e] + c + j;
        if (dst < 0 || dst >= total) return;
        int src = srcslot >> 3;
        if (src < 0 || src >= NTOK) return;
        if (t == 0) m_out[dst] = (float)e;
        const v2u* s2 = (const v2u*)(hs + (size_t)src * HID);
        v4u* d = (v4u*)(out + (size_t)dst * HID);
#pragma unroll
        for (int q = 0; q < 4; q++) {
            v2u w = s2[t + 256 * q];
            v4u a = {w.x << 16, w.x & 0xFFFF0000u, w.y << 16, w.y & 0xFFFF0000u};
            d[t + 256 * q] = a;
        }
    } else {
        // inv_perm: inv[v + sum_{f: last_f < v} pad_f] = pos(v); pads follow last slot.
        if (t < NG) {
            s_last[t] = ws[192 + t];
            s_pad[t] = ws[128 + t] - ws[64 + t];
        }
        __syncthreads();
        float* inv_out = out + (size_t)total * (HID + 1);
        int i = (b - NTOK - NG * BM) * 256 + t;
        int e = ids[i] & (NG - 1);
        int pos = ws[e] + (int)rank[i];
        int base = i;
#pragma unroll
        for (int f = 0; f < NG; f++) {
            int l = s_last[f];
            base += (l >= 0 && l < i) ? s_pad[f] : 0;
        }
        if (base < NSLOT) inv_out[base] = (float)pos;
        if (i == s_last[e]) {
            int oc = ws[e] + ws[64 + e];
            int pd = s_pad[e];
            for (int j = 0; j < pd; j++) {
                int idx = base + 1 + j;
                if (idx >= NSLOT) break;
                inv_out[idx] = (float)(oc + j);
            }
        }
    }
}

extern "C" void kernel_launch(void* const* d_in, const int* in_sizes, int n_in,
                              void* d_out, int out_size, void* d_ws, size_t ws_size,
                              hipStream_t stream) {
    const __hip_bfloat16* hs = (const __hip_bfloat16*)d_in[0];
    const int* ids = (const int*)d_in[1];
    float* out = (float*)d_out;  // mixed-dtype tuple => harness packs as float32

    int* ws = (int*)d_ws;
    unsigned short* rank = (unsigned short*)(ws + 8704);

    hipLaunchKernelGGL(hist_scan_k, dim3(NSEG), dim3(256), 0, stream, ids, ws);
    hipLaunchKernelGGL(rank_k, dim3(NSEG), dim3(64), 0, stream, ids, ws, rank);
    hipLaunchKernelGGL(copy_k, dim3(NTOK + NG * BM + NSLOT / 256), dim3(256), 0, stream,
                       hs, ids, ws, rank, out);
}